// Round 6
// baseline (460.324 us; speedup 1.0000x reference)
//
#include <hip/hip_runtime.h>
#include <hip/hip_bf16.h>

// Problem constants
#define S_LEN   1024
#define BATCH   4
#define DMODEL  2048
#define NHEADS  16
#define NKVH    8
#define HEADD   128
#define NTOK    4096      // BATCH*S_LEN
#define QKV_CH  4096      // 2048 q + 1024 k + 1024 v

typedef __bf16 bf16x8 __attribute__((ext_vector_type(8)));
typedef float  f32x4  __attribute__((ext_vector_type(4)));

__device__ __forceinline__ float bf2f(unsigned short u) {
    return __uint_as_float(((unsigned)u) << 16);
}
__device__ __forceinline__ ushort f2bu(float f) {
    union { __hip_bfloat16 h; ushort u; } c;
    c.h = __float2bfloat16(f);
    return c.u;
}
// async global->LDS, 16B per lane; LDS dest must be wave-contiguous in lane order
__device__ __forceinline__ void gl_lds16(const ushort* g, ushort* l) {
    __builtin_amdgcn_global_load_lds(
        (const __attribute__((address_space(1))) void*)g,
        (__attribute__((address_space(3))) void*)l,
        16, 0, 0);
}

// ---------------- fused weight casts: Wq/Wk/Wv/Wo/lA fp32 -> bf16 ----------------
// float4-group index space: Wq 1048576 | Wk 524288 | Wv 524288 | Wo 1048576 | lA 8192
__global__ __launch_bounds__(256) void wcast_kernel(const float* __restrict__ Wq,
                                                    const float* __restrict__ Wk,
                                                    const float* __restrict__ Wv,
                                                    const float* __restrict__ Wo,
                                                    const float* __restrict__ lA,
                                                    __hip_bfloat16* __restrict__ wqkv,
                                                    __hip_bfloat16* __restrict__ wo,
                                                    __hip_bfloat16* __restrict__ acat) {
    int i = blockIdx.x * 256 + threadIdx.x;
    const float* src; __hip_bfloat16* dst; int off;
    if (i < 1048576)      { src = Wq; dst = wqkv;           off = i; }
    else if (i < 1572864) { src = Wk; dst = wqkv + 4194304; off = i - 1048576; }
    else if (i < 2097152) { src = Wv; dst = wqkv + 6291456; off = i - 1572864; }
    else if (i < 3145728) { src = Wo; dst = wo;             off = i - 2097152; }
    else if (i < 3178496) { src = lA; dst = acat;           off = i - 3145728; }
    else return;
    float4 v = ((const float4*)src)[off];
    union { ushort4 u; __hip_bfloat16 h[4]; } r;
    r.h[0] = __float2bfloat16(v.x);
    r.h[1] = __float2bfloat16(v.y);
    r.h[2] = __float2bfloat16(v.z);
    r.h[3] = __float2bfloat16(v.w);
    ((ushort4*)dst)[off] = r.u;
}

// ---------------- lB (e,d,r) fp32 -> Bt[d][e*16+r] bf16 ----------------
__global__ __launch_bounds__(256) void btrans_kernel(const float* __restrict__ lB,
                                                     ushort* __restrict__ Bt) {
    int idx = blockIdx.x * 256 + threadIdx.x;   // 131072
    int d = idx >> 6, er = idx & 63;
    int e = er >> 4, r = er & 15;
    Bt[idx] = f2bu(lB[((size_t)e * DMODEL + d) * 16 + r]);
}

// ---------------- fused hidden cast + gate (block = one token) ----------------
__global__ __launch_bounds__(256) void gatecast_kernel(const float* __restrict__ X,
                                                       const float* __restrict__ GW,
                                                       __hip_bfloat16* __restrict__ Xb,
                                                       float* __restrict__ EW) {
    __shared__ float red[4][257];
    const int t = blockIdx.x, tid = threadIdx.x;
    const float* x = X + (size_t)t * DMODEL;
    __hip_bfloat16* xb = Xb + (size_t)t * DMODEL;
    float p0 = 0.f, p1 = 0.f, p2 = 0.f, p3 = 0.f;
#pragma unroll
    for (int c = 0; c < 2; c++) {
        int i4 = tid + c * 256;           // float4 group in row
        float4 v = ((const float4*)x)[i4];
        union { ushort4 u; __hip_bfloat16 h[4]; } r;
        r.h[0] = __float2bfloat16(v.x);
        r.h[1] = __float2bfloat16(v.y);
        r.h[2] = __float2bfloat16(v.z);
        r.h[3] = __float2bfloat16(v.w);
        ((ushort4*)xb)[i4] = r.u;
        int d = i4 * 4;
        const float* g0 = GW + d;
        p0 += v.x * g0[0] + v.y * g0[1] + v.z * g0[2] + v.w * g0[3];
        const float* g1 = GW + DMODEL + d;
        p1 += v.x * g1[0] + v.y * g1[1] + v.z * g1[2] + v.w * g1[3];
        const float* g2 = GW + 2 * DMODEL + d;
        p2 += v.x * g2[0] + v.y * g2[1] + v.z * g2[2] + v.w * g2[3];
        const float* g3 = GW + 3 * DMODEL + d;
        p3 += v.x * g3[0] + v.y * g3[1] + v.z * g3[2] + v.w * g3[3];
    }
    red[0][tid] = p0; red[1][tid] = p1; red[2][tid] = p2; red[3][tid] = p3;
    __syncthreads();
    for (int s = 128; s > 0; s >>= 1) {
        if (tid < s) {
            red[0][tid] += red[0][tid + s];
            red[1][tid] += red[1][tid + s];
            red[2][tid] += red[2][tid + s];
            red[3][tid] += red[3][tid + s];
        }
        __syncthreads();
    }
    if (tid == 0) {
        float l[4] = { red[0][0], red[1][0], red[2][0], red[3][0] };
        float mx = fmaxf(fmaxf(l[0], l[1]), fmaxf(l[2], l[3]));
        float pe[4], sum = 0.f;
        for (int e = 0; e < 4; e++) { pe[e] = __expf(l[e] - mx); sum += pe[e]; }
        float inv = 1.0f / sum;
        for (int e = 0; e < 4; e++) pe[e] *= inv;
        int i1 = 0;
        for (int e = 1; e < 4; e++) if (pe[e] > pe[i1]) i1 = e;
        int i2 = -1;
        for (int e = 0; e < 4; e++) if (e != i1 && (i2 < 0 || pe[e] > pe[i2])) i2 = e;
        float o[4] = {0.f, 0.f, 0.f, 0.f};
        o[i1] = pe[i1]; o[i2] = pe[i2];
        float* ew = EW + (size_t)t * 4;
        ew[0] = o[0]; ew[1] = o[1]; ew[2] = o[2]; ew[3] = o[3];
    }
}

// ---------------- QKV GEMM with fused RMSNorm+RoPE / V-transpose epilogue ----------------
// A: tokens x 2048 (bf16), B: 4096 x 2048 (Wq;Wk;Wv bf16). Each n-block is exactly one
// head's 128 channels; each m-block is 128 tokens of one batch. Writes Qb/Kb/Vt directly.
#define CP 132   // LDS C-tile pitch (ushorts): stride 66 dwords -> free 2-way bank alias
__global__ __launch_bounds__(256) void gemm_qkv_fused(const ushort* __restrict__ A,
                                                      const ushort* __restrict__ B,
                                                      const float* __restrict__ cosb,
                                                      const float* __restrict__ sinb,
                                                      const float* __restrict__ qnw,
                                                      const float* __restrict__ knw,
                                                      ushort* __restrict__ Qb,
                                                      ushort* __restrict__ Kb,
                                                      ushort* __restrict__ Vt) {
    __shared__ __align__(16) ushort smem[128 * CP];   // 33 KB; As/Bs overlay first 16 KB
    ushort* As = smem;
    ushort* Bs = smem + 4096;
    const int tid  = threadIdx.x;
    const int wave = tid >> 6, lane = tid & 63;
    const int l16  = lane & 15, quad = lane >> 4;
    const int m0 = blockIdx.y * 128, n0 = blockIdx.x * 128;
    const int wm = (wave >> 1) * 64, wn = (wave & 1) * 64;
    const int K = DMODEL;

    f32x4 acc[4][4];
#pragma unroll
    for (int i = 0; i < 4; i++)
#pragma unroll
        for (int j = 0; j < 4; j++) acc[i][j] = (f32x4){0.f, 0.f, 0.f, 0.f};

    const int r1 = tid >> 2, kg1 = (tid & 3) * 8;
    const int r2 = (tid + 256) >> 2, kg2 = ((tid + 256) & 3) * 8;

    for (int k0 = 0; k0 < K; k0 += 32) {
        __syncthreads();
        gl_lds16(A + (size_t)(m0 + r1) * K + k0 + kg1, As + tid * 8);
        gl_lds16(B + (size_t)(n0 + r1) * K + k0 + kg1, Bs + tid * 8);
        gl_lds16(A + (size_t)(m0 + r2) * K + k0 + kg2, As + (tid + 256) * 8);
        gl_lds16(B + (size_t)(n0 + r2) * K + k0 + kg2, Bs + (tid + 256) * 8);
        __syncthreads();
        bf16x8 af[4], bfr[4];
#pragma unroll
        for (int i = 0; i < 4; i++) {
            af[i]  = *(const bf16x8*)(As + (wm + i * 16 + l16) * 32 + quad * 8);
            bfr[i] = *(const bf16x8*)(Bs + (wn + i * 16 + l16) * 32 + quad * 8);
        }
#pragma unroll
        for (int i = 0; i < 4; i++)
#pragma unroll
            for (int j = 0; j < 4; j++)
                acc[i][j] = __builtin_amdgcn_mfma_f32_16x16x32_bf16(af[i], bfr[j], acc[i][j], 0, 0, 0);
    }

    // ---- epilogue: stage C tile (bf16) to LDS ----
    __syncthreads();
#pragma unroll
    for (int i = 0; i < 4; i++)
#pragma unroll
        for (int j = 0; j < 4; j++)
#pragma unroll
            for (int r = 0; r < 4; r++)
                smem[(wm + i * 16 + quad * 4 + r) * CP + wn + j * 16 + l16] = f2bu(acc[i][j][r]);
    __syncthreads();

    const int bloc = m0 >> 10, sbase = m0 & 1023;   // uniform: 128-tile never crosses batch

    if (n0 < 3072) {
        // q/k head: rmsnorm + rope. 2 threads per token row.
        const int row = tid >> 1, half = tid & 1;
        const int m = m0 + row;                      // token = b*1024+s
        const float* w = (n0 < 2048) ? qnw : knw;
        const float scale = (n0 < 2048) ? 0.08838834764831845f : 1.0f;
        ushort* dst;
        if (n0 < 2048) {
            int h = n0 >> 7;
            dst = Qb + ((size_t)((bloc * 16 + h) * 1024 + (m & 1023))) * HEADD;
        } else {
            int kv = (n0 - 2048) >> 7;
            dst = Kb + ((size_t)((bloc * 8 + kv) * 1024 + (m & 1023))) * HEADD;
        }
        const ushort* rowp = smem + row * CP;
        union { uint4 v; ushort u[8]; } mine[8], oth[8];
#pragma unroll
        for (int g = 0; g < 8; g++) {
            mine[g].v = *(const uint4*)(rowp + half * 64 + g * 8);
            oth[g].v  = *(const uint4*)(rowp + (half ^ 1) * 64 + g * 8);
        }
        float ssq = 0.f;
#pragma unroll
        for (int g = 0; g < 8; g++)
#pragma unroll
            for (int e = 0; e < 8; e++) { float v = bf2f(mine[g].u[e]); ssq += v * v; }
        ssq += __shfl_xor(ssq, 1);                  // partner lane holds other half
        float rstd = rsqrtf(ssq * (1.0f / 128.0f) + 1e-6f);
        const float* cp = cosb + (size_t)m * HEADD + half * 64;
        const float* sp = sinb + (size_t)m * HEADD + half * 64;
        const float* wme = w + half * 64;
        const float* wot = w + (half ? 0 : 64);
        const float sgn = half ? 1.0f : -1.0f;
#pragma unroll
        for (int g = 0; g < 8; g++) {
            union { ushort u[8]; uint4 v; } pk;
#pragma unroll
            for (int e = 0; e < 8; e++) {
                int d = g * 8 + e;
                float nm = bf2f(mine[g].u[e]) * rstd * wme[d];
                float no = bf2f(oth[g].u[e])  * rstd * wot[d];
                float o  = nm * cp[d] + sgn * no * sp[d];
                pk.u[e] = f2bu(o * scale);
            }
            *(uint4*)(dst + half * 64 + g * 8) = pk.v;
        }
    } else {
        // v head: transpose to Vt[b,kv,d,s]. 2 threads per d-channel.
        const int kv = (n0 - 3072) >> 7;
        const int d = tid >> 1, sh = tid & 1;
        ushort* dstv = Vt + ((size_t)((bloc * 8 + kv) * HEADD + d)) * S_LEN + sbase + sh * 64;
#pragma unroll
        for (int g = 0; g < 8; g++) {
            union { ushort u[8]; uint4 v; } pk;
#pragma unroll
            for (int j = 0; j < 8; j++)
                pk.u[j] = smem[(sh * 64 + g * 8 + j) * CP + d];
            *(uint4*)(dstv + g * 8) = pk.v;
        }
    }
}

// ---------------- Wo GEMM with fused LoRA delta: C = A*B^T + A2*B2^T (fp32 out) ----------------
__global__ __launch_bounds__(256) void gemm_bt_lora(const ushort* __restrict__ A,
                                                    const ushort* __restrict__ B,
                                                    const ushort* __restrict__ A2,
                                                    const ushort* __restrict__ B2,
                                                    float* __restrict__ C) {
    __shared__ ushort As[128 * 32];
    __shared__ ushort Bs[128 * 32];
    const int tid  = threadIdx.x;
    const int wave = tid >> 6, lane = tid & 63;
    const int l16  = lane & 15, quad = lane >> 4;
    const int m0 = blockIdx.y * 128, n0 = blockIdx.x * 128;
    const int wm = (wave >> 1) * 64, wn = (wave & 1) * 64;
    const int K = DMODEL, N = DMODEL;

    f32x4 acc[4][4];
#pragma unroll
    for (int i = 0; i < 4; i++)
#pragma unroll
        for (int j = 0; j < 4; j++) acc[i][j] = (f32x4){0.f, 0.f, 0.f, 0.f};

    const int r1 = tid >> 2, kg1 = (tid & 3) * 8;
    const int r2 = (tid + 256) >> 2, kg2 = ((tid + 256) & 3) * 8;

    for (int k0 = 0; k0 < K; k0 += 32) {
        __syncthreads();
        gl_lds16(A + (size_t)(m0 + r1) * K + k0 + kg1, As + tid * 8);
        gl_lds16(B + (size_t)(n0 + r1) * K + k0 + kg1, Bs + tid * 8);
        gl_lds16(A + (size_t)(m0 + r2) * K + k0 + kg2, As + (tid + 256) * 8);
        gl_lds16(B + (size_t)(n0 + r2) * K + k0 + kg2, Bs + (tid + 256) * 8);
        __syncthreads();
        bf16x8 af[4], bfr[4];
#pragma unroll
        for (int i = 0; i < 4; i++) {
            af[i]  = *(const bf16x8*)(As + (wm + i * 16 + l16) * 32 + quad * 8);
            bfr[i] = *(const bf16x8*)(Bs + (wn + i * 16 + l16) * 32 + quad * 8);
        }
#pragma unroll
        for (int i = 0; i < 4; i++)
#pragma unroll
            for (int j = 0; j < 4; j++)
                acc[i][j] = __builtin_amdgcn_mfma_f32_16x16x32_bf16(af[i], bfr[j], acc[i][j], 0, 0, 0);
    }

    // LoRA delta: 2 extra K-steps over K2=64
#pragma unroll
    for (int k0 = 0; k0 < 64; k0 += 32) {
        __syncthreads();
        gl_lds16(A2 + (size_t)(m0 + r1) * 64 + k0 + kg1, As + tid * 8);
        gl_lds16(B2 + (size_t)(n0 + r1) * 64 + k0 + kg1, Bs + tid * 8);
        gl_lds16(A2 + (size_t)(m0 + r2) * 64 + k0 + kg2, As + (tid + 256) * 8);
        gl_lds16(B2 + (size_t)(n0 + r2) * 64 + k0 + kg2, Bs + (tid + 256) * 8);
        __syncthreads();
        bf16x8 af[4], bfr[4];
#pragma unroll
        for (int i = 0; i < 4; i++) {
            af[i]  = *(const bf16x8*)(As + (wm + i * 16 + l16) * 32 + quad * 8);
            bfr[i] = *(const bf16x8*)(Bs + (wn + i * 16 + l16) * 32 + quad * 8);
        }
#pragma unroll
        for (int i = 0; i < 4; i++)
#pragma unroll
            for (int j = 0; j < 4; j++)
                acc[i][j] = __builtin_amdgcn_mfma_f32_16x16x32_bf16(af[i], bfr[j], acc[i][j], 0, 0, 0);
    }

#pragma unroll
    for (int i = 0; i < 4; i++)
#pragma unroll
        for (int j = 0; j < 4; j++)
#pragma unroll
            for (int r = 0; r < 4; r++) {
                int m = m0 + wm + i * 16 + quad * 4 + r;
                int n = n0 + wn + j * 16 + l16;
                C[(size_t)m * N + n] = acc[i][j][r];
            }
}

// ---------------- LoRA H: G[t][e*16+r] = bf16(2*ew[t][e] * (x_t . A[e][r])) ----------------
__global__ __launch_bounds__(256) void lora_h_kernel(const ushort* __restrict__ X,
                                                     const ushort* __restrict__ Acat,
                                                     const float* __restrict__ EW,
                                                     ushort* __restrict__ G) {
    __shared__ ushort As[64 * 32];
    __shared__ ushort Bs[64 * 32];
    const int tid = threadIdx.x;
    const int wave = tid >> 6, lane = tid & 63;
    const int l16 = lane & 15, quad = lane >> 4;
    const int m0 = blockIdx.x * 64;

    f32x4 acc[4];
#pragma unroll
    for (int nt = 0; nt < 4; nt++) acc[nt] = (f32x4){0.f, 0.f, 0.f, 0.f};

    const int r1 = tid >> 2, kg1 = (tid & 3) * 8;

    for (int k0 = 0; k0 < DMODEL; k0 += 32) {
        __syncthreads();
        gl_lds16(X + (size_t)(m0 + r1) * DMODEL + k0 + kg1, As + tid * 8);
        gl_lds16(Acat + (size_t)r1 * DMODEL + k0 + kg1, Bs + tid * 8);
        __syncthreads();
        bf16x8 af = *(const bf16x8*)(As + (wave * 16 + l16) * 32 + quad * 8);
#pragma unroll
        for (int nt = 0; nt < 4; nt++) {
            bf16x8 bfr = *(const bf16x8*)(Bs + (nt * 16 + l16) * 32 + quad * 8);
            acc[nt] = __builtin_amdgcn_mfma_f32_16x16x32_bf16(af, bfr, acc[nt], 0, 0, 0);
        }
    }
#pragma unroll
    for (int nt = 0; nt < 4; nt++)
#pragma unroll
        for (int r = 0; r < 4; r++) {
            int m = m0 + wave * 16 + quad * 4 + r;
            float wsc = 2.0f * EW[(size_t)m * 4 + nt];   // LORA_SCALE=2 folded
            G[(size_t)m * 64 + nt * 16 + l16] = f2bu(acc[nt][r] * wsc);
        }
}

// ---------------- flash attention (bf16 MFMA, no-max softmax — exact by boundedness) ----------------
// |q|=|k|=sqrt(128) after rmsnorm, scale 1/sqrt(128) => |s|<=11.4, exp(s)<=9e4: fp32/bf16 safe.
#define KPITCH 136
#define VPITCH 72
__global__ __launch_bounds__(256) void fattn_kernel(const ushort* __restrict__ Qb,
                                                    const ushort* __restrict__ Kb,
                                                    const ushort* __restrict__ Vt,
                                                    __hip_bfloat16* __restrict__ O) {
    __shared__ __align__(16) ushort Ks[64 * KPITCH];
    __shared__ __align__(16) ushort Vs[128 * VPITCH];
    __shared__ __align__(16) ushort Ps[4 * 16 * VPITCH];
    const int tid = threadIdx.x;
    const int wq = tid >> 6, lane = tid & 63;
    const int l16 = lane & 15, quad = lane >> 4;
    const int qblk = 15 - (blockIdx.x >> 6);    // heavy q-blocks first
    const int bh = blockIdx.x & 63;
    const int b = bh >> 4, h = bh & 15;
    const int kvb = b * 8 + (h >> 1);
    const int q0 = qblk * 64;
    const int qbase = q0 + wq * 16;

    bf16x8 qf[4];
    const ushort* qrow = Qb + ((size_t)bh * S_LEN + qbase + l16) * HEADD;
#pragma unroll
    for (int kt = 0; kt < 4; kt++)
        qf[kt] = *(const bf16x8*)(qrow + kt * 32 + quad * 8);

    f32x4 oacc[8];
#pragma unroll
    for (int dt = 0; dt < 8; dt++) oacc[dt] = (f32x4){0.f, 0.f, 0.f, 0.f};
    float l[4] = { 0.f, 0.f, 0.f, 0.f };   // per-lane partial denominators

    const ushort* kbase = Kb + (size_t)kvb * S_LEN * HEADD;
    const ushort* vbase = Vt + (size_t)kvb * HEADD * S_LEN;
    const int ntiles = qblk + 1;

    for (int kb = 0; kb < ntiles; kb++) {
        const int k0 = kb * 64;
        __syncthreads();
        for (int c = tid; c < 1024; c += 256) {
            int row = c >> 4, col = (c & 15) * 8;
            *(uint4*)(Ks + row * KPITCH + col) =
                *(const uint4*)(kbase + (size_t)(k0 + row) * HEADD + col);
        }
        for (int c = tid; c < 1024; c += 256) {
            int row = c >> 3, col = (c & 7) * 8;
            *(uint4*)(Vs + row * VPITCH + col) =
                *(const uint4*)(vbase + (size_t)row * S_LEN + k0 + col);
        }
        __syncthreads();

        f32x4 sacc[4];
#pragma unroll
        for (int nt = 0; nt < 4; nt++) sacc[nt] = (f32x4){0.f, 0.f, 0.f, 0.f};
#pragma unroll
        for (int kt = 0; kt < 4; kt++) {
#pragma unroll
            for (int nt = 0; nt < 4; nt++) {
                bf16x8 kf = *(const bf16x8*)(Ks + (nt * 16 + l16) * KPITCH + kt * 32 + quad * 8);
                sacc[nt] = __builtin_amdgcn_mfma_f32_16x16x32_bf16(qf[kt], kf, sacc[nt], 0, 0, 0);
            }
        }

        // p = exp(s) (no max subtraction), causal mask, accumulate partial l
#pragma unroll
        for (int r = 0; r < 4; r++) {
            const int qg = qbase + quad * 4 + r;
#pragma unroll
            for (int nt = 0; nt < 4; nt++) {
                int kg = k0 + nt * 16 + l16;
                float p = (kg <= qg) ? __expf(sacc[nt][r]) : 0.f;
                l[r] += p;
                Ps[wq * 16 * VPITCH + (quad * 4 + r) * VPITCH + nt * 16 + l16] = f2bu(p);
            }
        }

        // O += P V (unnormalized, no rescale needed)
#pragma unroll
        for (int kt2 = 0; kt2 < 2; kt2++) {
            bf16x8 pf = *(const bf16x8*)(Ps + wq * 16 * VPITCH + l16 * VPITCH + kt2 * 32 + quad * 8);
#pragma unroll
            for (int dt = 0; dt < 8; dt++) {
                bf16x8 vf = *(const bf16x8*)(Vs + (dt * 16 + l16) * VPITCH + kt2 * 32 + quad * 8);
                oacc[dt] = __builtin_amdgcn_mfma_f32_16x16x32_bf16(pf, vf, oacc[dt], 0, 0, 0);
            }
        }
    }

    // epilogue: reduce l across the 16-lane key groups, normalize, store
#pragma unroll
    for (int r = 0; r < 4; r++) {
        float lr = l[r];
        lr += __shfl_xor(lr, 1);
        lr += __shfl_xor(lr, 2);
        lr += __shfl_xor(lr, 4);
        lr += __shfl_xor(lr, 8);
        float inv = 1.0f / lr;
        size_t base = ((size_t)(b * S_LEN + qbase + quad * 4 + r)) * (NHEADS * HEADD) + h * HEADD;
#pragma unroll
        for (int dt = 0; dt < 8; dt++)
            O[base + dt * 16 + l16] = __float2bfloat16(oacc[dt][r] * inv);
    }
}

extern "C" void kernel_launch(void* const* d_in, const int* in_sizes, int n_in,
                              void* d_out, int out_size, void* d_ws, size_t ws_size,
                              hipStream_t stream) {
    const float* hidden = (const float*)d_in[0];
    const float* cosb   = (const float*)d_in[1];
    const float* sinb   = (const float*)d_in[2];
    const float* Wq     = (const float*)d_in[3];
    const float* Wk     = (const float*)d_in[4];
    const float* Wv     = (const float*)d_in[5];
    const float* Wo     = (const float*)d_in[6];
    const float* qnw    = (const float*)d_in[7];
    const float* knw    = (const float*)d_in[8];
    const float* gw     = (const float*)d_in[9];
    const float* lA     = (const float*)d_in[10];
    const float* lB     = (const float*)d_in[11];
    float* out = (float*)d_out;

    // workspace layout (~96 MB, no aliasing — Qb/Kb/Vt written while hid/wqkv still live):
    char* ws = (char*)d_ws;
    __hip_bfloat16* hid_bf  = (__hip_bfloat16*)ws;                  // [0,16M)
    __hip_bfloat16* wqkv_bf = (__hip_bfloat16*)(ws + (16u << 20));  // [16,32)
    __hip_bfloat16* wo_bf   = (__hip_bfloat16*)(ws + (32u << 20));  // [32,40)
    __hip_bfloat16* attn_bf = (__hip_bfloat16*)(ws + (40u << 20));  // [40,56)
    ushort*         Acat    = (ushort*)(ws + (56u << 20));                 // 256 KB
    ushort*         Bt      = (ushort*)(ws + (56u << 20) + (256u << 10));  // 256 KB
    ushort*         G       = (ushort*)(ws + (56u << 20) + (512u << 10));  // 512 KB
    ushort*         Qb      = (ushort*)(ws + (64u << 20));          // [64,80)
    ushort*         Kb      = (ushort*)(ws + (80u << 20));          // [80,88)
    ushort*         Vt      = (ushort*)(ws + (88u << 20));          // [88,96)
    float*          ew      = (float*)(ws + (96u << 20));           // 64 KB

    // 1. fused weight casts (Wq/Wk/Wv/Wo/lA)
    wcast_kernel<<<12416, 256, 0, stream>>>(Wq, Wk, Wv, Wo, lA,
                                            wqkv_bf, wo_bf, (__hip_bfloat16*)Acat);
    // 2. fused hidden cast + gate
    gatecast_kernel<<<4096, 256, 0, stream>>>(hidden, gw, hid_bf, ew);
    // 3. LoRA B transpose
    btrans_kernel<<<512, 256, 0, stream>>>(lB, Bt);

    // 4. QKV projection with fused rmsnorm/rope/transpose -> Qb/Kb/Vt
    gemm_qkv_fused<<<dim3(32, 32), 256, 0, stream>>>((const ushort*)hid_bf, (const ushort*)wqkv_bf,
                                                     cosb, sinb, qnw, knw, Qb, Kb, Vt);

    // 5. flash attention -> attn_bf
    fattn_kernel<<<1024, 256, 0, stream>>>(Qb, Kb, Vt, attn_bf);

    // 6. LoRA H: G = 2*ew*(attn @ Acat^T)  (M=4096, N=64, K=2048)
    lora_h_kernel<<<64, 256, 0, stream>>>((const ushort*)attn_bf, Acat, ew, G);

    // 7. output projection + fused LoRA delta -> d_out
    gemm_bt_lora<<<dim3(16, 32), 256, 0, stream>>>((const ushort*)attn_bf, (const ushort*)wo_bf,
                                                   G, Bt, out);
}

// Round 7
// 407.557 us; speedup vs baseline: 1.1295x; 1.1295x over previous
//
#include <hip/hip_runtime.h>
#include <hip/hip_bf16.h>

// Problem constants
#define S_LEN   1024
#define BATCH   4
#define DMODEL  2048
#define NHEADS  16
#define NKVH    8
#define HEADD   128
#define NTOK    4096      // BATCH*S_LEN
#define QKV_CH  4096      // 2048 q + 1024 k + 1024 v

typedef __bf16 bf16x8 __attribute__((ext_vector_type(8)));
typedef float  f32x4  __attribute__((ext_vector_type(4)));

__device__ __forceinline__ float bf2f(unsigned short u) {
    return __uint_as_float(((unsigned)u) << 16);
}
__device__ __forceinline__ ushort f2bu(float f) {
    union { __hip_bfloat16 h; ushort u; } c;
    c.h = __float2bfloat16(f);
    return c.u;
}
// async global->LDS, 16B per lane; LDS dest must be wave-contiguous in lane order
__device__ __forceinline__ void gl_lds16(const ushort* g, ushort* l) {
    __builtin_amdgcn_global_load_lds(
        (const __attribute__((address_space(1))) void*)g,
        (__attribute__((address_space(3))) void*)l,
        16, 0, 0);
}

// ---------------- fused weight casts: Wq/Wk/Wv/Wo/lA fp32 -> bf16 ----------------
__global__ __launch_bounds__(256) void wcast_kernel(const float* __restrict__ Wq,
                                                    const float* __restrict__ Wk,
                                                    const float* __restrict__ Wv,
                                                    const float* __restrict__ Wo,
                                                    const float* __restrict__ lA,
                                                    __hip_bfloat16* __restrict__ wqkv,
                                                    __hip_bfloat16* __restrict__ wo,
                                                    __hip_bfloat16* __restrict__ acat) {
    int i = blockIdx.x * 256 + threadIdx.x;
    const float* src; __hip_bfloat16* dst; int off;
    if (i < 1048576)      { src = Wq; dst = wqkv;           off = i; }
    else if (i < 1572864) { src = Wk; dst = wqkv + 4194304; off = i - 1048576; }
    else if (i < 2097152) { src = Wv; dst = wqkv + 6291456; off = i - 1572864; }
    else if (i < 3145728) { src = Wo; dst = wo;             off = i - 2097152; }
    else if (i < 3178496) { src = lA; dst = acat;           off = i - 3145728; }
    else return;
    float4 v = ((const float4*)src)[off];
    union { ushort4 u; __hip_bfloat16 h[4]; } r;
    r.h[0] = __float2bfloat16(v.x);
    r.h[1] = __float2bfloat16(v.y);
    r.h[2] = __float2bfloat16(v.z);
    r.h[3] = __float2bfloat16(v.w);
    ((ushort4*)dst)[off] = r.u;
}

// ---------------- lB (e,d,r) fp32 -> Bt[d][e*16+r] bf16 ----------------
__global__ __launch_bounds__(256) void btrans_kernel(const float* __restrict__ lB,
                                                     ushort* __restrict__ Bt) {
    int idx = blockIdx.x * 256 + threadIdx.x;   // 131072
    int d = idx >> 6, er = idx & 63;
    int e = er >> 4, r = er & 15;
    Bt[idx] = f2bu(lB[((size_t)e * DMODEL + d) * 16 + r]);
}

// ---------------- fused hidden cast + gate (block = one token) ----------------
__global__ __launch_bounds__(256) void gatecast_kernel(const float* __restrict__ X,
                                                       const float* __restrict__ GW,
                                                       __hip_bfloat16* __restrict__ Xb,
                                                       float* __restrict__ EW) {
    __shared__ float red[4][257];
    const int t = blockIdx.x, tid = threadIdx.x;
    const float* x = X + (size_t)t * DMODEL;
    __hip_bfloat16* xb = Xb + (size_t)t * DMODEL;
    float p0 = 0.f, p1 = 0.f, p2 = 0.f, p3 = 0.f;
#pragma unroll
    for (int c = 0; c < 2; c++) {
        int i4 = tid + c * 256;           // float4 group in row
        float4 v = ((const float4*)x)[i4];
        union { ushort4 u; __hip_bfloat16 h[4]; } r;
        r.h[0] = __float2bfloat16(v.x);
        r.h[1] = __float2bfloat16(v.y);
        r.h[2] = __float2bfloat16(v.z);
        r.h[3] = __float2bfloat16(v.w);
        ((ushort4*)xb)[i4] = r.u;
        int d = i4 * 4;
        const float* g0 = GW + d;
        p0 += v.x * g0[0] + v.y * g0[1] + v.z * g0[2] + v.w * g0[3];
        const float* g1 = GW + DMODEL + d;
        p1 += v.x * g1[0] + v.y * g1[1] + v.z * g1[2] + v.w * g1[3];
        const float* g2 = GW + 2 * DMODEL + d;
        p2 += v.x * g2[0] + v.y * g2[1] + v.z * g2[2] + v.w * g2[3];
        const float* g3 = GW + 3 * DMODEL + d;
        p3 += v.x * g3[0] + v.y * g3[1] + v.z * g3[2] + v.w * g3[3];
    }
    red[0][tid] = p0; red[1][tid] = p1; red[2][tid] = p2; red[3][tid] = p3;
    __syncthreads();
    for (int s = 128; s > 0; s >>= 1) {
        if (tid < s) {
            red[0][tid] += red[0][tid + s];
            red[1][tid] += red[1][tid + s];
            red[2][tid] += red[2][tid + s];
            red[3][tid] += red[3][tid + s];
        }
        __syncthreads();
    }
    if (tid == 0) {
        float l[4] = { red[0][0], red[1][0], red[2][0], red[3][0] };
        float mx = fmaxf(fmaxf(l[0], l[1]), fmaxf(l[2], l[3]));
        float pe[4], sum = 0.f;
        for (int e = 0; e < 4; e++) { pe[e] = __expf(l[e] - mx); sum += pe[e]; }
        float inv = 1.0f / sum;
        for (int e = 0; e < 4; e++) pe[e] *= inv;
        int i1 = 0;
        for (int e = 1; e < 4; e++) if (pe[e] > pe[i1]) i1 = e;
        int i2 = -1;
        for (int e = 0; e < 4; e++) if (e != i1 && (i2 < 0 || pe[e] > pe[i2])) i2 = e;
        float o[4] = {0.f, 0.f, 0.f, 0.f};
        o[i1] = pe[i1]; o[i2] = pe[i2];
        float* ew = EW + (size_t)t * 4;
        ew[0] = o[0]; ew[1] = o[1]; ew[2] = o[2]; ew[3] = o[3];
    }
}

// ---------------- bf16 MFMA GEMM: C[M][N] = A[M][K] * B[N][K]^T (fp32 C, coalesced) ----------------
// 128x128 tile, 4 waves, global_load_lds staging (m97 structure). Round-4 proven: 103 us.
__global__ __launch_bounds__(256) void gemm_bt(const ushort* __restrict__ A,
                                               const ushort* __restrict__ B,
                                               float* __restrict__ C,
                                               int M, int N, int K) {
    __shared__ ushort As[128 * 32];
    __shared__ ushort Bs[128 * 32];
    const int tid  = threadIdx.x;
    const int wave = tid >> 6, lane = tid & 63;
    const int l16  = lane & 15, quad = lane >> 4;
    const int m0 = blockIdx.y * 128, n0 = blockIdx.x * 128;
    const int wm = (wave >> 1) * 64, wn = (wave & 1) * 64;

    f32x4 acc[4][4];
#pragma unroll
    for (int i = 0; i < 4; i++)
#pragma unroll
        for (int j = 0; j < 4; j++) acc[i][j] = (f32x4){0.f, 0.f, 0.f, 0.f};

    const int r1 = tid >> 2, kg1 = (tid & 3) * 8;
    const int r2 = (tid + 256) >> 2, kg2 = ((tid + 256) & 3) * 8;

    for (int k0 = 0; k0 < K; k0 += 32) {
        __syncthreads();
        gl_lds16(A + (size_t)(m0 + r1) * K + k0 + kg1, As + tid * 8);
        gl_lds16(B + (size_t)(n0 + r1) * K + k0 + kg1, Bs + tid * 8);
        gl_lds16(A + (size_t)(m0 + r2) * K + k0 + kg2, As + (tid + 256) * 8);
        gl_lds16(B + (size_t)(n0 + r2) * K + k0 + kg2, Bs + (tid + 256) * 8);
        __syncthreads();
        bf16x8 af[4], bfr[4];
#pragma unroll
        for (int i = 0; i < 4; i++) {
            af[i]  = *(const bf16x8*)(As + (wm + i * 16 + l16) * 32 + quad * 8);
            bfr[i] = *(const bf16x8*)(Bs + (wn + i * 16 + l16) * 32 + quad * 8);
        }
#pragma unroll
        for (int i = 0; i < 4; i++)
#pragma unroll
            for (int j = 0; j < 4; j++)
                acc[i][j] = __builtin_amdgcn_mfma_f32_16x16x32_bf16(af[i], bfr[j], acc[i][j], 0, 0, 0);
    }
#pragma unroll
    for (int i = 0; i < 4; i++)
#pragma unroll
        for (int j = 0; j < 4; j++)
#pragma unroll
            for (int r = 0; r < 4; r++) {
                int m = m0 + wm + i * 16 + quad * 4 + r;
                int n = n0 + wn + j * 16 + l16;
                C[(size_t)m * N + n] = acc[i][j][r];
            }
}

// ---------------- Wo GEMM with fused LoRA delta: C = A*B^T + A2*B2^T (fp32 out) ----------------
__global__ __launch_bounds__(256) void gemm_bt_lora(const ushort* __restrict__ A,
                                                    const ushort* __restrict__ B,
                                                    const ushort* __restrict__ A2,
                                                    const ushort* __restrict__ B2,
                                                    float* __restrict__ C) {
    __shared__ ushort As[128 * 32];
    __shared__ ushort Bs[128 * 32];
    const int tid  = threadIdx.x;
    const int wave = tid >> 6, lane = tid & 63;
    const int l16  = lane & 15, quad = lane >> 4;
    const int m0 = blockIdx.y * 128, n0 = blockIdx.x * 128;
    const int wm = (wave >> 1) * 64, wn = (wave & 1) * 64;
    const int K = DMODEL, N = DMODEL;

    f32x4 acc[4][4];
#pragma unroll
    for (int i = 0; i < 4; i++)
#pragma unroll
        for (int j = 0; j < 4; j++) acc[i][j] = (f32x4){0.f, 0.f, 0.f, 0.f};

    const int r1 = tid >> 2, kg1 = (tid & 3) * 8;
    const int r2 = (tid + 256) >> 2, kg2 = ((tid + 256) & 3) * 8;

    for (int k0 = 0; k0 < K; k0 += 32) {
        __syncthreads();
        gl_lds16(A + (size_t)(m0 + r1) * K + k0 + kg1, As + tid * 8);
        gl_lds16(B + (size_t)(n0 + r1) * K + k0 + kg1, Bs + tid * 8);
        gl_lds16(A + (size_t)(m0 + r2) * K + k0 + kg2, As + (tid + 256) * 8);
        gl_lds16(B + (size_t)(n0 + r2) * K + k0 + kg2, Bs + (tid + 256) * 8);
        __syncthreads();
        bf16x8 af[4], bfr[4];
#pragma unroll
        for (int i = 0; i < 4; i++) {
            af[i]  = *(const bf16x8*)(As + (wm + i * 16 + l16) * 32 + quad * 8);
            bfr[i] = *(const bf16x8*)(Bs + (wn + i * 16 + l16) * 32 + quad * 8);
        }
#pragma unroll
        for (int i = 0; i < 4; i++)
#pragma unroll
            for (int j = 0; j < 4; j++)
                acc[i][j] = __builtin_amdgcn_mfma_f32_16x16x32_bf16(af[i], bfr[j], acc[i][j], 0, 0, 0);
    }

    // LoRA delta: 2 extra K-steps over K2=64
#pragma unroll
    for (int k0 = 0; k0 < 64; k0 += 32) {
        __syncthreads();
        gl_lds16(A2 + (size_t)(m0 + r1) * 64 + k0 + kg1, As + tid * 8);
        gl_lds16(B2 + (size_t)(n0 + r1) * 64 + k0 + kg1, Bs + tid * 8);
        gl_lds16(A2 + (size_t)(m0 + r2) * 64 + k0 + kg2, As + (tid + 256) * 8);
        gl_lds16(B2 + (size_t)(n0 + r2) * 64 + k0 + kg2, Bs + (tid + 256) * 8);
        __syncthreads();
        bf16x8 af[4], bfr[4];
#pragma unroll
        for (int i = 0; i < 4; i++) {
            af[i]  = *(const bf16x8*)(As + (wm + i * 16 + l16) * 32 + quad * 8);
            bfr[i] = *(const bf16x8*)(Bs + (wn + i * 16 + l16) * 32 + quad * 8);
        }
#pragma unroll
        for (int i = 0; i < 4; i++)
#pragma unroll
            for (int j = 0; j < 4; j++)
                acc[i][j] = __builtin_amdgcn_mfma_f32_16x16x32_bf16(af[i], bfr[j], acc[i][j], 0, 0, 0);
    }

#pragma unroll
    for (int i = 0; i < 4; i++)
#pragma unroll
        for (int j = 0; j < 4; j++)
#pragma unroll
            for (int r = 0; r < 4; r++) {
                int m = m0 + wm + i * 16 + quad * 4 + r;
                int n = n0 + wn + j * 16 + l16;
                C[(size_t)m * N + n] = acc[i][j][r];
            }
}

// ---------------- LoRA H: G[t][e*16+r] = bf16(2*ew[t][e] * (x_t . A[e][r])) ----------------
__global__ __launch_bounds__(256) void lora_h_kernel(const ushort* __restrict__ X,
                                                     const ushort* __restrict__ Acat,
                                                     const float* __restrict__ EW,
                                                     ushort* __restrict__ G) {
    __shared__ ushort As[64 * 32];
    __shared__ ushort Bs[64 * 32];
    const int tid = threadIdx.x;
    const int wave = tid >> 6, lane = tid & 63;
    const int l16 = lane & 15, quad = lane >> 4;
    const int m0 = blockIdx.x * 64;

    f32x4 acc[4];
#pragma unroll
    for (int nt = 0; nt < 4; nt++) acc[nt] = (f32x4){0.f, 0.f, 0.f, 0.f};

    const int r1 = tid >> 2, kg1 = (tid & 3) * 8;

    for (int k0 = 0; k0 < DMODEL; k0 += 32) {
        __syncthreads();
        gl_lds16(X + (size_t)(m0 + r1) * DMODEL + k0 + kg1, As + tid * 8);
        gl_lds16(Acat + (size_t)r1 * DMODEL + k0 + kg1, Bs + tid * 8);
        __syncthreads();
        bf16x8 af = *(const bf16x8*)(As + (wave * 16 + l16) * 32 + quad * 8);
#pragma unroll
        for (int nt = 0; nt < 4; nt++) {
            bf16x8 bfr = *(const bf16x8*)(Bs + (nt * 16 + l16) * 32 + quad * 8);
            acc[nt] = __builtin_amdgcn_mfma_f32_16x16x32_bf16(af, bfr, acc[nt], 0, 0, 0);
        }
    }
#pragma unroll
    for (int nt = 0; nt < 4; nt++)
#pragma unroll
        for (int r = 0; r < 4; r++) {
            int m = m0 + wave * 16 + quad * 4 + r;
            float wsc = 2.0f * EW[(size_t)m * 4 + nt];   // LORA_SCALE=2 folded
            G[(size_t)m * 64 + nt * 16 + l16] = f2bu(acc[nt][r] * wsc);
        }
}

// ---------------- RMSNorm + RoPE: fp32 qkv -> bf16 Qb[b,h,s,d] (scaled), Kb[b,kv,s,d] ----------------
__global__ __launch_bounds__(256) void normrope_kernel(const float* __restrict__ QKV,
                                                       const float* __restrict__ cosb,
                                                       const float* __restrict__ sinb,
                                                       const float* __restrict__ qw,
                                                       const float* __restrict__ kw,
                                                       ushort* __restrict__ Qb,
                                                       ushort* __restrict__ Kb) {
    const int wave = threadIdx.x >> 6, lane = threadIdx.x & 63;
    const int r = blockIdx.x * 4 + wave;
    const float* p; const float* w; int t; ushort* dst; float scale;
    if (r < NTOK * NHEADS) {
        t = r >> 4;
        int h = r & 15;
        p = QKV + (size_t)t * QKV_CH + h * HEADD;
        w = qw; scale = 0.08838834764831845f;   // 128^-0.5 folded into Q
        int b = t >> 10, s = t & 1023;
        dst = Qb + ((size_t)((b * 16 + h) * 1024 + s)) * HEADD;
    } else {
        int r2 = r - NTOK * NHEADS;
        t = r2 >> 3;
        int kv = r2 & 7;
        p = QKV + (size_t)t * QKV_CH + 2048 + kv * HEADD;
        w = kw; scale = 1.0f;
        int b = t >> 10, s = t & 1023;
        dst = Kb + ((size_t)((b * 8 + kv) * 1024 + s)) * HEADD;
    }
    float xl = p[lane], xh = p[lane + 64];
    float ss = xl * xl + xh * xh;
#pragma unroll
    for (int mask = 1; mask < 64; mask <<= 1) ss += __shfl_xor(ss, mask);
    float rstd = rsqrtf(ss * (1.0f / 128.0f) + 1e-6f);
    float nl = xl * rstd * w[lane];
    float nh = xh * rstd * w[lane + 64];
    const float* cp = cosb + (size_t)t * HEADD;
    const float* sp = sinb + (size_t)t * HEADD;
    float ol = nl * cp[lane]      - nh * sp[lane];
    float oh = nh * cp[lane + 64] + nl * sp[lane + 64];
    dst[lane]      = f2bu(ol * scale);
    dst[lane + 64] = f2bu(oh * scale);
}

// ---------------- V transpose: fp32 qkv v -> bf16 Vt[b,kv,d,s] ----------------
__global__ __launch_bounds__(256) void vtrans_kernel(const float* __restrict__ QKV,
                                                     ushort* __restrict__ Vt) {
    __shared__ float Ts[64][129];
    const int blk = blockIdx.x;          // 4*8*16
    const int sc = blk & 15;
    const int kvb = blk >> 4;            // b*8+kv
    const int s0 = sc * 64;
    const float* src = QKV + ((size_t)((kvb >> 3) * 1024 + s0)) * QKV_CH + 3072 + (kvb & 7) * HEADD;
    for (int c = threadIdx.x; c < 2048; c += 256) {
        int s = c >> 5, d0 = (c & 31) * 4;
        float4 v = *(const float4*)(src + (size_t)s * QKV_CH + d0);
        Ts[s][d0] = v.x; Ts[s][d0 + 1] = v.y; Ts[s][d0 + 2] = v.z; Ts[s][d0 + 3] = v.w;
    }
    __syncthreads();
    ushort* dst = Vt + ((size_t)kvb * HEADD) * S_LEN + s0;
    for (int c = threadIdx.x; c < 1024; c += 256) {
        int d = c >> 3, s8 = (c & 7) * 8;
        union { ushort u[8]; uint4 v; } pk;
#pragma unroll
        for (int j = 0; j < 8; j++) pk.u[j] = f2bu(Ts[s8 + j][d]);
        *(uint4*)(dst + (size_t)d * S_LEN + s8) = pk.v;
    }
}

// ---------------- flash attention (bf16 MFMA, no-max softmax — exact by boundedness) ----------------
// |q|=|k|=sqrt(128) after rmsnorm, scale 1/sqrt(128) => |s|<=11.4, exp(s)<=9e4: fp32/bf16 safe.
#define KPITCH 136
#define VPITCH 72
__global__ __launch_bounds__(256) void fattn_kernel(const ushort* __restrict__ Qb,
                                                    const ushort* __restrict__ Kb,
                                                    const ushort* __restrict__ Vt,
                                                    __hip_bfloat16* __restrict__ O) {
    __shared__ __align__(16) ushort Ks[64 * KPITCH];
    __shared__ __align__(16) ushort Vs[128 * VPITCH];
    __shared__ __align__(16) ushort Ps[4 * 16 * VPITCH];
    const int tid = threadIdx.x;
    const int wq = tid >> 6, lane = tid & 63;
    const int l16 = lane & 15, quad = lane >> 4;
    const int qblk = 15 - (blockIdx.x >> 6);    // heavy q-blocks first
    const int bh = blockIdx.x & 63;
    const int b = bh >> 4, h = bh & 15;
    const int kvb = b * 8 + (h >> 1);
    const int q0 = qblk * 64;
    const int qbase = q0 + wq * 16;

    bf16x8 qf[4];
    const ushort* qrow = Qb + ((size_t)bh * S_LEN + qbase + l16) * HEADD;
#pragma unroll
    for (int kt = 0; kt < 4; kt++)
        qf[kt] = *(const bf16x8*)(qrow + kt * 32 + quad * 8);

    f32x4 oacc[8];
#pragma unroll
    for (int dt = 0; dt < 8; dt++) oacc[dt] = (f32x4){0.f, 0.f, 0.f, 0.f};
    float l[4] = { 0.f, 0.f, 0.f, 0.f };   // per-lane partial denominators

    const ushort* kbase = Kb + (size_t)kvb * S_LEN * HEADD;
    const ushort* vbase = Vt + (size_t)kvb * HEADD * S_LEN;
    const int ntiles = qblk + 1;

    for (int kb = 0; kb < ntiles; kb++) {
        const int k0 = kb * 64;
        __syncthreads();
        for (int c = tid; c < 1024; c += 256) {
            int row = c >> 4, col = (c & 15) * 8;
            *(uint4*)(Ks + row * KPITCH + col) =
                *(const uint4*)(kbase + (size_t)(k0 + row) * HEADD + col);
        }
        for (int c = tid; c < 1024; c += 256) {
            int row = c >> 3, col = (c & 7) * 8;
            *(uint4*)(Vs + row * VPITCH + col) =
                *(const uint4*)(vbase + (size_t)row * S_LEN + k0 + col);
        }
        __syncthreads();

        f32x4 sacc[4];
#pragma unroll
        for (int nt = 0; nt < 4; nt++) sacc[nt] = (f32x4){0.f, 0.f, 0.f, 0.f};
#pragma unroll
        for (int kt = 0; kt < 4; kt++) {
#pragma unroll
            for (int nt = 0; nt < 4; nt++) {
                bf16x8 kf = *(const bf16x8*)(Ks + (nt * 16 + l16) * KPITCH + kt * 32 + quad * 8);
                sacc[nt] = __builtin_amdgcn_mfma_f32_16x16x32_bf16(qf[kt], kf, sacc[nt], 0, 0, 0);
            }
        }

        // p = exp(s) (no max subtraction), causal mask, accumulate partial l
#pragma unroll
        for (int r = 0; r < 4; r++) {
            const int qg = qbase + quad * 4 + r;
#pragma unroll
            for (int nt = 0; nt < 4; nt++) {
                int kg = k0 + nt * 16 + l16;
                float p = (kg <= qg) ? __expf(sacc[nt][r]) : 0.f;
                l[r] += p;
                Ps[wq * 16 * VPITCH + (quad * 4 + r) * VPITCH + nt * 16 + l16] = f2bu(p);
            }
        }

        // O += P V (unnormalized, no rescale needed)
#pragma unroll
        for (int kt2 = 0; kt2 < 2; kt2++) {
            bf16x8 pf = *(const bf16x8*)(Ps + wq * 16 * VPITCH + l16 * VPITCH + kt2 * 32 + quad * 8);
#pragma unroll
            for (int dt = 0; dt < 8; dt++) {
                bf16x8 vf = *(const bf16x8*)(Vs + (dt * 16 + l16) * VPITCH + kt2 * 32 + quad * 8);
                oacc[dt] = __builtin_amdgcn_mfma_f32_16x16x32_bf16(pf, vf, oacc[dt], 0, 0, 0);
            }
        }
    }

    // epilogue: reduce l across the 16-lane key groups, normalize, store
#pragma unroll
    for (int r = 0; r < 4; r++) {
        float lr = l[r];
        lr += __shfl_xor(lr, 1);
        lr += __shfl_xor(lr, 2);
        lr += __shfl_xor(lr, 4);
        lr += __shfl_xor(lr, 8);
        float inv = 1.0f / lr;
        size_t base = ((size_t)(b * S_LEN + qbase + quad * 4 + r)) * (NHEADS * HEADD) + h * HEADD;
#pragma unroll
        for (int dt = 0; dt < 8; dt++)
            O[base + dt * 16 + l16] = __float2bfloat16(oacc[dt][r] * inv);
    }
}

extern "C" void kernel_launch(void* const* d_in, const int* in_sizes, int n_in,
                              void* d_out, int out_size, void* d_ws, size_t ws_size,
                              hipStream_t stream) {
    const float* hidden = (const float*)d_in[0];
    const float* cosb   = (const float*)d_in[1];
    const float* sinb   = (const float*)d_in[2];
    const float* Wq     = (const float*)d_in[3];
    const float* Wk     = (const float*)d_in[4];
    const float* Wv     = (const float*)d_in[5];
    const float* Wo     = (const float*)d_in[6];
    const float* qnw    = (const float*)d_in[7];
    const float* knw    = (const float*)d_in[8];
    const float* gw     = (const float*)d_in[9];
    const float* lA     = (const float*)d_in[10];
    const float* lB     = (const float*)d_in[11];
    float* out = (float*)d_out;

    // workspace layout (~105.1 MB, lifetime-aliased; r1/r2 proved >=120 MB available):
    //  [0,16M):    hid_bf (dead after QKV gemm)   -> Qb (normrope)
    //  [16M,32M):  wqkv_bf (dead after QKV gemm)  -> Kb [16,24) + Vt [24,32)
    //  [32M,40M):  wo_bf (live to final gemm)
    //  [40M,104M): qkv fp32 (dead after normrope+vtrans) -> attn_bf [40,56)
    //  [104M,+):   Acat 256K | Bt 256K | G 512K | ew 64K   (written at prep time)
    char* ws = (char*)d_ws;
    __hip_bfloat16* hid_bf  = (__hip_bfloat16*)ws;
    __hip_bfloat16* wqkv_bf = (__hip_bfloat16*)(ws + (16u << 20));
    __hip_bfloat16* wo_bf   = (__hip_bfloat16*)(ws + (32u << 20));
    float*          qkv     = (float*)(ws + (40u << 20));
    __hip_bfloat16* attn_bf = (__hip_bfloat16*)(ws + (40u << 20));  // alias qkv (after dead)
    ushort*         Qb      = (ushort*)ws;                          // alias hid_bf
    ushort*         Kb      = (ushort*)(ws + (16u << 20));          // alias wqkv_bf[0:8M)
    ushort*         Vt      = (ushort*)(ws + (24u << 20));          // alias wqkv_bf[8M:16M)
    ushort*         Acat    = (ushort*)(ws + (104u << 20));                 // 256 KB
    ushort*         Bt      = (ushort*)(ws + (104u << 20) + (256u << 10));  // 256 KB
    ushort*         G       = (ushort*)(ws + (104u << 20) + (512u << 10));  // 512 KB
    float*          ew      = (float*)(ws + (105u << 20));                  // 64 KB

    // 1. fused weight casts (Wq/Wk/Wv/Wo/lA)
    wcast_kernel<<<12416, 256, 0, stream>>>(Wq, Wk, Wv, Wo, lA,
                                            wqkv_bf, wo_bf, (__hip_bfloat16*)Acat);
    // 2. fused hidden cast + gate
    gatecast_kernel<<<4096, 256, 0, stream>>>(hidden, gw, hid_bf, ew);
    // 3. LoRA B transpose
    btrans_kernel<<<512, 256, 0, stream>>>(lB, Bt);

    // 4. fused QKV projection (M=4096, N=4096, K=2048) -> fp32 qkv
    gemm_bt<<<dim3(32, 32), 256, 0, stream>>>((const ushort*)hid_bf, (const ushort*)wqkv_bf,
                                              qkv, NTOK, QKV_CH, DMODEL);

    // 5. RMSNorm + RoPE -> Qb/Kb ; V transpose -> Vt (qkv dead after these)
    normrope_kernel<<<24576, 256, 0, stream>>>(qkv, cosb, sinb, qnw, knw, Qb, Kb);
    vtrans_kernel<<<512, 256, 0, stream>>>(qkv, Vt);

    // 6. flash attention -> attn_bf
    fattn_kernel<<<1024, 256, 0, stream>>>(Qb, Kb, Vt, attn_bf);

    // 7. LoRA H: G = 2*ew*(attn @ Acat^T)  (M=4096, N=64, K=2048)
    lora_h_kernel<<<64, 256, 0, stream>>>((const ushort*)attn_bf, Acat, ew, G);

    // 8. output projection + fused LoRA delta -> d_out
    gemm_bt_lora<<<dim3(16, 32), 256, 0, stream>>>((const ushort*)attn_bf, (const ushort*)wo_bf,
                                                   G, Bt, out);
}